// Round 2
// baseline (184.558 us; speedup 1.0000x reference)
//
#include <hip/hip_runtime.h>

typedef __attribute__((ext_vector_type(8))) short bf16x8;
typedef __attribute__((ext_vector_type(4))) float f32x4;

#define NTOT 16384
#define MCODES 2048
#define DDIM 256

__device__ __forceinline__ unsigned short f2bf(float f) {
  union { float f; unsigned u; } v; v.f = f;
  unsigned r = v.u + 0x7FFFu + ((v.u >> 16) & 1u);   // RNE
  return (unsigned short)(r >> 16);
}

#define GLOAD16(gptr, lptr) \
  __builtin_amdgcn_global_load_lds((const __attribute__((address_space(1))) void*)(gptr), \
                                   (__attribute__((address_space(3))) void*)(lptr), 16, 0, 0)

// ---------------- prep e: bf16 convert + ||e||^2 + colmin/zsq init ----------------
// grid 512 x 256 threads; wave per row (4 rows/block)
__global__ void prep_e_k(const float* __restrict__ e, unsigned short* __restrict__ ebf,
                         float* __restrict__ esq, unsigned* __restrict__ colmin,
                         float* __restrict__ zsq) {
  if (blockIdx.x < 64) zsq[blockIdx.x * 256 + threadIdx.x] = 0.0f;  // 64*256 = 16384
  int row = blockIdx.x * 4 + (threadIdx.x >> 6);
  int lane = threadIdx.x & 63;
  const float4 v = *(const float4*)(e + (size_t)row * DDIM + lane * 4);
  ushort4 o;
  o.x = f2bf(v.x); o.y = f2bf(v.y); o.z = f2bf(v.z); o.w = f2bf(v.w);
  *(ushort4*)(ebf + (size_t)row * DDIM + lane * 4) = o;
  float s = v.x * v.x + v.y * v.y + v.z * v.z + v.w * v.w;
  #pragma unroll
  for (int off = 32; off; off >>= 1) s += __shfl_xor(s, off, 64);
  if (lane == 0) {
    esq[row] = s;
    colmin[row] = 0x7F800000u;  // +inf
  }
}

// ---------------- transpose z (B,D,H,W) f32 -> (N,D) bf16, fused ||z||^2 ----------------
// grid (4 d-tiles, 16 hw-tiles, 16 b), 256 threads, 64x64 tile
__global__ void trans_zsq_k(const float* __restrict__ z, unsigned short* __restrict__ zf,
                            float* __restrict__ zsq) {
  __shared__ float t[64][65];                       // +1 pad: 2-way max on both phases
  const int b = blockIdx.z, d0 = blockIdx.x * 64, hw0 = blockIdx.y * 64;
  const int tid = threadIdx.x;
  {
    const int dl = tid >> 4, hwl = (tid & 15) * 4;
    const float* src = z + (size_t)b * 262144 + (size_t)(d0 + dl) * 1024 + hw0 + hwl;
    #pragma unroll
    for (int it = 0; it < 4; ++it) {
      float4 v = *(const float4*)(src + (size_t)it * 16 * 1024);
      *(float4*)&t[it * 16 + dl][hwl] = v;
    }
  }
  __syncthreads();
  const int hwl = tid >> 3;                          // 0..31
  const int dl = (tid & 7) * 8;                      // 0..56 step 8
  #pragma unroll
  for (int p = 0; p < 2; ++p) {
    const int hw = p * 32 + hwl;
    float vv[8];
    float s = 0.0f;
    #pragma unroll
    for (int u = 0; u < 8; ++u) { vv[u] = t[dl + u][hw]; s += vv[u] * vv[u]; }
    bf16x8 pk;
    #pragma unroll
    for (int u = 0; u < 8; ++u) pk[u] = (short)f2bf(vv[u]);
    const size_t n = (size_t)b * 1024 + hw0 + hw;
    *(bf16x8*)(zf + n * DDIM + d0 + dl) = pk;
    // 8 adjacent lanes share hw -> partial sum over this block's 64 d's
    s += __shfl_xor(s, 1, 64);
    s += __shfl_xor(s, 2, 64);
    s += __shfl_xor(s, 4, 64);
    if ((tid & 7) == 0) atomicAdd(zsq + n, s);
  }
}

// ---------------- GEMM 128x128, BK=64, 2-phase prefetch, T2 swizzle, fused epilogue ----------------
__global__ __launch_bounds__(256, 2) void gemm_k(
    const unsigned short* __restrict__ A,   // zf (N x 256) bf16
    const unsigned short* __restrict__ B,   // e  (M x 256) bf16
    const float* __restrict__ zsq, const float* __restrict__ esq,
    unsigned* __restrict__ colmin, float* __restrict__ out) {
  __shared__ unsigned short lds[2][2 * 128 * 64];   // [buf][A:8192 | B:8192] shorts = 64 KB
  const int tid = threadIdx.x;
  const int wave = tid >> 6, lane = tid & 63;
  const int wm = wave >> 1, wn = wave & 1;
  const int row0 = blockIdx.y * 128, col0 = blockIdx.x * 128;

  // staging: 4 chunks x (256 thr x 16B) per matrix per K-tile.
  // LDS dest is linear (row-major [128][64]); source column pre-swizzled (rule #21).
  const int sr = tid >> 3;                                   // 0..31 within chunk
  const int scs = ((tid & 7) * 8) ^ ((sr & 7) * 8);          // swizzled k-col (bf16 units)
  size_t aOff[4], bOff[4];
  #pragma unroll
  for (int c = 0; c < 4; ++c) {
    aOff[c] = (size_t)(row0 + c * 32 + sr) * DDIM + scs;
    bOff[c] = (size_t)(col0 + c * 32 + sr) * DDIM + scs;
  }

  // ds_read fragment addressing (XOR matches source pre-swizzle)
  const int rA = wm * 64 + (lane & 15);
  const int rB = wn * 64 + (lane & 15);
  const int slot = (lane >> 4) * 16;                 // byte slot within 128B row
  const int swz = (lane & 7) << 4;                   // (row&7)<<4

  f32x4 acc[4][4] = {};

  #define STAGE(buf, k0)                                                    \
    {                                                                       \
      unsigned short* la = &lds[buf][0];                                    \
      unsigned short* lb = &lds[buf][8192];                                 \
      _Pragma("unroll")                                                     \
      for (int c = 0; c < 4; ++c) {                                         \
        GLOAD16(A + aOff[c] + (k0), la + c * 2048 + wave * 512);            \
        GLOAD16(B + bOff[c] + (k0), lb + c * 2048 + wave * 512);            \
      }                                                                     \
    }

  STAGE(0, 0);
  __syncthreads();
  #pragma unroll
  for (int t = 0; t < 4; ++t) {
    const int cur = t & 1;
    if (t < 3) STAGE(cur ^ 1, (t + 1) * 64);         // prefetch overlaps MFMA below
    const char* pA = (const char*)&lds[cur][0];
    const char* pB = (const char*)&lds[cur][8192];
    bf16x8 av[2][4], bv[2][4];
    #pragma unroll
    for (int kk = 0; kk < 2; ++kk) {
      #pragma unroll
      for (int i = 0; i < 4; ++i)
        av[kk][i] = *(const bf16x8*)(pA + (rA + i * 16) * 128 + ((kk * 64 + slot) ^ swz));
      #pragma unroll
      for (int j = 0; j < 4; ++j)
        bv[kk][j] = *(const bf16x8*)(pB + (rB + j * 16) * 128 + ((kk * 64 + slot) ^ swz));
    }
    #pragma unroll
    for (int kk = 0; kk < 2; ++kk)
      #pragma unroll
      for (int i = 0; i < 4; ++i)
        #pragma unroll
        for (int j = 0; j < 4; ++j)
          acc[i][j] = __builtin_amdgcn_mfma_f32_16x16x32_bf16(av[kk][i], bv[kk][j], acc[i][j], 0, 0, 0);
    if (t < 3) __syncthreads();                       // drains vmcnt(0): next tile landed
  }
  #undef STAGE

  // epilogue: dist = zsq + esq - 2*cross, clamp>=0, NT store + column-min
  const int r0 = lane >> 4, c = lane & 15;
  float cmin[4] = {3.4e38f, 3.4e38f, 3.4e38f, 3.4e38f};
  #pragma unroll
  for (int j = 0; j < 4; ++j) {
    const int col = col0 + wn * 64 + j * 16 + c;
    const float es = esq[col];
    #pragma unroll
    for (int i = 0; i < 4; ++i) {
      const int row = row0 + wm * 64 + i * 16 + r0 * 4;
      const float4 zs = *(const float4*)(zsq + row);
      const float d0 = fmaxf(zs.x + es - 2.0f * acc[i][j][0], 0.0f);
      const float d1 = fmaxf(zs.y + es - 2.0f * acc[i][j][1], 0.0f);
      const float d2 = fmaxf(zs.z + es - 2.0f * acc[i][j][2], 0.0f);
      const float d3 = fmaxf(zs.w + es - 2.0f * acc[i][j][3], 0.0f);
      __builtin_nontemporal_store(d0, &out[(size_t)(row + 0) * MCODES + col]);
      __builtin_nontemporal_store(d1, &out[(size_t)(row + 1) * MCODES + col]);
      __builtin_nontemporal_store(d2, &out[(size_t)(row + 2) * MCODES + col]);
      __builtin_nontemporal_store(d3, &out[(size_t)(row + 3) * MCODES + col]);
      cmin[j] = fminf(cmin[j], fminf(fminf(d0, d1), fminf(d2, d3)));
    }
  }
  #pragma unroll
  for (int j = 0; j < 4; ++j) {
    float m = cmin[j];
    m = fminf(m, __shfl_xor(m, 16, 64));
    m = fminf(m, __shfl_xor(m, 32, 64));
    if (lane < 16) {
      const int col = col0 + wn * 64 + j * 16 + lane;
      atomicMin(colmin + col, __float_as_uint(m));   // dist >= 0 -> uint order == float order
    }
  }
}

// ---------------- loss = mean(colmin) ----------------
__global__ void loss_k(const unsigned* __restrict__ colmin, float* __restrict__ loss) {
  __shared__ float sdata[4];
  int t = threadIdx.x;
  float s = 0.0f;
  for (int i = t; i < MCODES; i += 256) s += __uint_as_float(colmin[i]);
  #pragma unroll
  for (int off = 32; off; off >>= 1) s += __shfl_down(s, off, 64);
  if ((t & 63) == 0) sdata[t >> 6] = s;
  __syncthreads();
  if (t == 0) loss[0] = (sdata[0] + sdata[1] + sdata[2] + sdata[3]) * (1.0f / (float)MCODES);
}

extern "C" void kernel_launch(void* const* d_in, const int* in_sizes, int n_in,
                              void* d_out, int out_size, void* d_ws, size_t ws_size,
                              hipStream_t stream) {
  const float* z = (const float*)d_in[0];
  const float* e = (const float*)d_in[1];
  float* out = (float*)d_out;

  float* ws = (float*)d_ws;
  float* zsq = ws;                                   // 16384 f
  float* esq = ws + NTOT;                            // 2048 f
  unsigned* colmin = (unsigned*)(ws + NTOT + MCODES);// 2048 u32
  unsigned short* ebf = (unsigned short*)(ws + NTOT + 2 * MCODES);  // 1 MB
  unsigned short* zf = ebf + (size_t)MCODES * DDIM;                 // 8 MB

  prep_e_k<<<MCODES / 4, 256, 0, stream>>>(e, ebf, esq, colmin, zsq);
  trans_zsq_k<<<dim3(4, 16, 16), 256, 0, stream>>>(z, zf, zsq);
  gemm_k<<<dim3(MCODES / 128, NTOT / 128), 256, 0, stream>>>(zf, ebf, zsq, esq, colmin, out);
  loss_k<<<1, 256, 0, stream>>>(colmin, out + (size_t)NTOT * MCODES);
}